// Round 8
// baseline (140.799 us; speedup 1.0000x reference)
//
#include <hip/hip_runtime.h>
#include <math.h>

// Problem constants (fixed by reference): B=32, T=2048, D=128
constexpr int B  = 32;
constexpr int T  = 2048;
constexpr int D  = 128;
constexpr int TS = 64;     // steps per tile
constexpr int NT = 4;      // tiles per wave -> wave covers 256 steps
constexpr int WD = 16;     // d-columns per wave

// Software-pipelined autonomous wave (R6 tile geometry, 4 tiles deep).
//   wave = 64 lanes = 16 step-groups x 4 d-quads = 64 steps x 16 d per tile
//   lane = 4 steps x 4 consecutive d per tile; wave processes 4 consecutive
//   tiles (256 steps) with triple-buffered register tiles:
//     iter k: [issue loads tile k+2] [summaries+ballots tile k+1]
//             [resolve carries / interp / store tile k]
//   Forward carry crosses tiles IN REGISTERS (no memory); backward carry
//   uses tile k+1's 64-step column summary (serial-fallback P ~= 2^-64).
//   Only the wave's outer edges probe a 16-step halo + gather -- once per
//   256 steps instead of once per 64 (R6). This interleaves load-issue and
//   compute inside each wave, breaking the grid-wide phase convoy that held
//   R0/R3/R4/R6 at ~46-52 us with all pipes <45% busy.
__global__ __launch_bounds__(256, 2)
void interp_pipe_kernel(const float* __restrict__ values,
                       const float* __restrict__ times,
                       const int*   __restrict__ mask,
                       float*       __restrict__ out)
{
    const int tid  = threadIdx.x;
    const int lane = tid & 63;
    const int g    = lane >> 2;            // step-group 0..15
    const int q    = lane & 3;             // d-quad
    const int waveId = (blockIdx.x << 2) | (tid >> 6);
    const int db  = waveId & 7;            // d-block of 16
    const int seg = (waveId >> 3) & 7;     // 256-step segment
    const int b   = waveId >> 6;
    const int d0  = db * WD + q * 4;
    const int s0  = seg * (NT * TS);
    const size_t bbase = (size_t)b * T * D;
    const unsigned long long colmask = 0x1111111111111111ull << q;

    float4 v4[3][4]; float4 t4[3][4]; int4 m4[3][4];   // triple-buffered tiles
    float Slv[2][4], Slt[2][4], Sfv[2][4], Sft[2][4];  // summaries (slot = tile&1)
    unsigned long long Gb[2][4];                        // column ballots
    unsigned mbits[2][4];                               // own 4-step obs bits
    float Fx[4], Ft[4];                                 // running forward carry

#define VCc(BK,i,j) ((&v4[BK][i].x)[j])
#define TCc(BK,i,j) ((&t4[BK][i].x)[j])
#define MCc(BK,i,j) ((&m4[BK][i].x)[j])

#define LOADT(BK, st_) do { \
    const size_t base_ = bbase + (size_t)((st_) + g * 4) * D + d0; \
    _Pragma("unroll") \
    for (int i_ = 0; i_ < 4; ++i_) { \
        v4[BK][i_] = *reinterpret_cast<const float4*>(values + base_ + (size_t)i_ * D); \
        t4[BK][i_] = *reinterpret_cast<const float4*>(times  + base_ + (size_t)i_ * D); \
        m4[BK][i_] = *reinterpret_cast<const int4*>(mask    + base_ + (size_t)i_ * D); \
    } } while (0)

#define SUMMT(BK, SL) do { \
    _Pragma("unroll") \
    for (int j_ = 0; j_ < 4; ++j_) { \
        unsigned mm_ = 0; \
        _Pragma("unroll") \
        for (int i_ = 0; i_ < 4; ++i_) mm_ |= (MCc(BK,i_,j_) != 0 ? 1u : 0u) << i_; \
        mbits[SL][j_] = mm_; \
        float a_ = 0.f, c_ = 0.f, e_ = 0.f, h_ = 0.f; \
        _Pragma("unroll") \
        for (int i_ = 0; i_ < 4; ++i_) \
            if ((mm_ >> i_) & 1u) { a_ = VCc(BK,i_,j_); c_ = TCc(BK,i_,j_); } \
        _Pragma("unroll") \
        for (int i_ = 3; i_ >= 0; --i_) \
            if ((mm_ >> i_) & 1u) { e_ = VCc(BK,i_,j_); h_ = TCc(BK,i_,j_); } \
        Slv[SL][j_] = a_; Slt[SL][j_] = c_; \
        Sfv[SL][j_] = e_; Sft[SL][j_] = h_; \
        Gb[SL][j_]  = __ballot(mm_ != 0u); \
    } } while (0)

// verified fill+interp math (identical to rounds 0-6); results written into VCc
#define FILL_INTERP(BK, j_, mbk_, cfx_, cft_, cbx_, cbt_) do { \
    float xl_[4], tlv_[4]; float cf_ = cfx_, ctv_ = cft_; \
    _Pragma("unroll") \
    for (int i_ = 0; i_ < 4; ++i_) { \
        if ((mbk_ >> i_) & 1u) { cf_ = VCc(BK,i_,j_); ctv_ = TCc(BK,i_,j_); } \
        xl_[i_] = cf_; tlv_[i_] = ctv_; } \
    float cb_ = cbx_, cbt2_ = cbt_; \
    _Pragma("unroll") \
    for (int i_ = 3; i_ >= 0; --i_) { \
        const bool obs_ = (mbk_ >> i_) & 1u; \
        if (obs_) { cb_ = VCc(BK,i_,j_); cbt2_ = TCc(BK,i_,j_); } \
        const float den_ = cbt2_ - tlv_[i_]; \
        const float num_ = xl_[i_] * (cbt2_ - TCc(BK,i_,j_)) + cb_ * (TCc(BK,i_,j_) - tlv_[i_]); \
        const bool safe_ = (den_ != 0.f); \
        float xi_ = num_ / (safe_ ? den_ : 1.f); \
        xi_ = (safe_ && isfinite(xi_)) ? xi_ : 0.f; \
        VCc(BK,i_,j_) = obs_ ? VCc(BK,i_,j_) : xi_; } \
    } while (0)

#define STORET(BK, K) do { \
    float* orow_ = out + bbase + (size_t)(s0 + (K) * TS + g * 4) * D + d0; \
    _Pragma("unroll") \
    for (int i_ = 0; i_ < 4; ++i_) \
        *reinterpret_cast<float4*>(orow_ + (size_t)i_ * D) = v4[BK][i_]; \
    } while (0)

// interior tile: backward from tile k+1's summary (slot SN)
#define PROCN(K, BK, SK, SN) do { \
    _Pragma("unroll") \
    for (int j_ = 0; j_ < 4; ++j_) { \
        const int dj_ = d0 + j_; \
        const unsigned long long col_   = Gb[SK][j_] & colmask; \
        const unsigned long long below_ = col_ & ((1ull << lane) - 1ull); \
        const unsigned long long above_ = col_ & ~((2ull << lane) - 1ull); \
        const unsigned long long colN_  = Gb[SN][j_] & colmask; \
        const int rF_ = below_ ? (63 - __builtin_clzll(below_)) : lane; \
        const int rB_ = above_ ? __builtin_ctzll(above_) : lane; \
        const int rN_ = colN_  ? __builtin_ctzll(colN_)  : lane; \
        const int rU_ = col_   ? (63 - __builtin_clzll(col_)) : lane; \
        const float gLV_ = __shfl(Slv[SK][j_], rF_, 64); \
        const float gLT_ = __shfl(Slt[SK][j_], rF_, 64); \
        const float gFV_ = __shfl(Sfv[SK][j_], rB_, 64); \
        const float gFT_ = __shfl(Sft[SK][j_], rB_, 64); \
        const float nFV_ = __shfl(Sfv[SN][j_], rN_, 64); \
        const float nFT_ = __shfl(Sft[SN][j_], rN_, 64); \
        const float uLV_ = __shfl(Slv[SK][j_], rU_, 64); \
        const float uLT_ = __shfl(Slt[SK][j_], rU_, 64); \
        const float cfx_ = below_ ? gLV_ : Fx[j_]; \
        const float cft_ = below_ ? gLT_ : Ft[j_]; \
        float cbx_, cbt_; \
        if (above_)      { cbx_ = gFV_; cbt_ = gFT_; } \
        else if (colN_)  { cbx_ = nFV_; cbt_ = nFT_; } \
        else { /* P ~= 2^-64: whole next tile column empty */ \
            bool fnd_ = false; cbx_ = 0.f; cbt_ = 0.f; \
            for (int st_ = s0 + ((K) + 2) * TS; st_ < T; ++st_) { \
                if (mask[bbase + (size_t)st_ * D + dj_] != 0) { \
                    const size_t o_ = bbase + (size_t)st_ * D + dj_; \
                    cbx_ = values[o_]; cbt_ = times[o_]; fnd_ = true; break; } } \
            if (!fnd_) { cbx_ = 0.f; cbt_ = times[bbase + (size_t)(T - 1) * D + dj_]; } \
        } \
        const unsigned mbk_ = mbits[SK][j_]; \
        FILL_INTERP(BK, j_, mbk_, cfx_, cft_, cbx_, cbt_); \
        if (col_) { Fx[j_] = uLV_; Ft[j_] = uLT_; } \
    } \
    STORET(BK, K); } while (0)

    // ================= prologue =================
    LOADT(0, s0);
    int4 hp4; hp4.x = 0; hp4.y = 0; hp4.z = 0; hp4.w = 0;
    int4 hn4; hn4.x = 0; hn4.y = 0; hn4.z = 0; hn4.w = 0;
    const bool haveHp = (seg > 0), haveHn = (seg < 7);
    if (haveHp) hp4 = *reinterpret_cast<const int4*>(
        mask + bbase + (size_t)(s0 - 16 + g) * D + db * WD + q * 4);
    if (haveHn) hn4 = *reinterpret_cast<const int4*>(
        mask + bbase + (size_t)(s0 + NT * TS + g) * D + db * WD + q * 4);
    LOADT(1, s0 + TS);
    SUMMT(0, 0);

    // forward-carry init (halo ballot -> broadcast gather; rare serial fallback)
#pragma unroll
    for (int j = 0; j < 4; ++j) {
        const int dj = d0 + j;
        const unsigned long long hp = __ballot(haveHp && (((&hp4.x)[j]) != 0));
        const unsigned long long hcol = hp & colmask;
        if (hcol) {
            const int st = s0 - 16 + ((63 - __builtin_clzll(hcol)) >> 2);
            const size_t o = bbase + (size_t)st * D + dj;
            Fx[j] = values[o]; Ft[j] = times[o];
        } else if (haveHp) {
            bool fnd = false; Fx[j] = 0.f; Ft[j] = 0.f;
            for (int st = s0 - 17; st >= 0; --st) {      // P ~= 2^-16, ~never
                if (mask[bbase + (size_t)st * D + dj] != 0) {
                    const size_t o = bbase + (size_t)st * D + dj;
                    Fx[j] = values[o]; Ft[j] = times[o]; fnd = true; break; }
            }
            if (!fnd) { Fx[j] = 0.f; Ft[j] = times[bbase + dj]; }   // ref init
        } else {
            Fx[j] = 0.f; Ft[j] = times[bbase + dj];                  // ref init
        }
    }

    // ================= pipelined main loop (fully unrolled) =================
    LOADT(2, s0 + 2 * TS);     // issue tile2
    SUMMT(1, 1);               // summaries tile1 (loads covered by prologue work)
    PROCN(0, 0, 0, 1);         // process tile0, store

    LOADT(0, s0 + 3 * TS);     // buf0 free -> issue tile3
    SUMMT(2, 0);               // summaries tile2 (covered by SUMMT(1)+PROCN(0))
    PROCN(1, 1, 1, 0);         // process tile1, store

    SUMMT(0, 1);               // summaries tile3 (covered by SUMMT(2)+PROCN(1))
    PROCN(2, 2, 0, 1);         // process tile2, store

    // ---- last tile: backward via next-halo ----
    {
        const int K = 3, BK = 0, SK = 1;
        (void)K;
#pragma unroll
        for (int j_ = 0; j_ < 4; ++j_) {
            const int dj_ = d0 + j_;
            const unsigned long long col_   = Gb[SK][j_] & colmask;
            const unsigned long long below_ = col_ & ((1ull << lane) - 1ull);
            const unsigned long long above_ = col_ & ~((2ull << lane) - 1ull);
            const int rF_ = below_ ? (63 - __builtin_clzll(below_)) : lane;
            const int rB_ = above_ ? __builtin_ctzll(above_) : lane;
            const float gLV_ = __shfl(Slv[SK][j_], rF_, 64);
            const float gLT_ = __shfl(Slt[SK][j_], rF_, 64);
            const float gFV_ = __shfl(Sfv[SK][j_], rB_, 64);
            const float gFT_ = __shfl(Sft[SK][j_], rB_, 64);
            const unsigned long long hn = __ballot(haveHn && (((&hn4.x)[j_]) != 0));
            const unsigned long long hcol_ = hn & colmask;
            const float cfx_ = below_ ? gLV_ : Fx[j_];
            const float cft_ = below_ ? gLT_ : Ft[j_];
            float cbx_, cbt_;
            if (above_) { cbx_ = gFV_; cbt_ = gFT_; }
            else if (hcol_) {
                const int st_ = s0 + NT * TS + ((int)__builtin_ctzll(hcol_) >> 2);
                const size_t o_ = bbase + (size_t)st_ * D + dj_;
                cbx_ = values[o_]; cbt_ = times[o_];
            } else {
                bool fnd_ = false; cbx_ = 0.f; cbt_ = 0.f;
                const int start_ = haveHn ? (s0 + NT * TS + 16) : T;
                for (int st_ = start_; st_ < T; ++st_) {   // P ~= 2^-16, ~never
                    if (mask[bbase + (size_t)st_ * D + dj_] != 0) {
                        const size_t o_ = bbase + (size_t)st_ * D + dj_;
                        cbx_ = values[o_]; cbt_ = times[o_]; fnd_ = true; break; }
                }
                if (!fnd_) { cbx_ = 0.f; cbt_ = times[bbase + (size_t)(T - 1) * D + dj_]; }
            }
            const unsigned mbk_ = mbits[SK][j_];
            FILL_INTERP(BK, j_, mbk_, cfx_, cft_, cbx_, cbt_);
        }
        STORET(BK, 3);
    }
}

extern "C" void kernel_launch(void* const* d_in, const int* in_sizes, int n_in,
                              void* d_out, int out_size, void* d_ws, size_t ws_size,
                              hipStream_t stream)
{
    const float* values = (const float*)d_in[0];
    const float* times  = (const float*)d_in[1];
    const int*   mask   = (const int*)d_in[2];
    float*       out    = (float*)d_out;

    // 32 b x 8 segments x 8 d-blocks = 2048 waves = 512 blocks of 256
    const int blocks = (B * (T / (NT * TS)) * (D / WD) * 64) / 256;
    interp_pipe_kernel<<<blocks, 256, 0, stream>>>(values, times, mask, out);
}